// Round 1
// baseline (3731.298 us; speedup 1.0000x reference)
//
#include <hip/hip_runtime.h>

#define NPOINT 2048
#define NSAMPLE 32
#define NPTS 8192
#define NB 4
#define CH 16
#define FPS_THREADS 512
#define PTS_PER_THREAD (NPTS / FPS_THREADS) /* 16 */
#define FPS_WAVES (FPS_THREADS / 64)        /* 8 */

// Output layout (flat float32, concatenated in reference return order)
#define OFF_NEWXYZ 0
#define OFF_NEWPTS (NB * NPOINT * 3)                          /* 24576 */
#define OFF_IDX (OFF_NEWPTS + NB * NPOINT * NSAMPLE * CH)     /* 4218880 */
#define OFF_GXYZ (OFF_IDX + NB * NPOINT * NSAMPLE)            /* 4481024 */

// ---------------- FPS: one block per batch, sequential 2048-step scan ------
// Reference semantics: idxs[0]=0; each step: dists=min(dists,|p-p_last|^2),
// next = argmax(dists) with FIRST-index tie-break. Op order mirrored:
// (dx*dx + dy*dy) + dz*dz, no fma contraction.
__global__ __launch_bounds__(FPS_THREADS) void fps_kernel(
    const float* __restrict__ in, float* __restrict__ out) {
  __shared__ float redv[FPS_WAVES];
  __shared__ int redi[FPS_WAVES];

  const int b = blockIdx.x;
  const int tid = threadIdx.x;
  const int lane = tid & 63;
  const int wv = tid >> 6;
  const float* base = in + (size_t)b * NPTS * CH;

  // Strided ownership: thread t owns points t, t+512, ... (coalesced loads,
  // ascending index within thread so strict '>' keeps lowest index on tie).
  float px[PTS_PER_THREAD], py[PTS_PER_THREAD], pz[PTS_PER_THREAD],
      d[PTS_PER_THREAD];
#pragma unroll
  for (int j = 0; j < PTS_PER_THREAD; ++j) {
    int p = tid + j * FPS_THREADS;
    float4 r = *reinterpret_cast<const float4*>(base + (size_t)p * CH);
    px[j] = r.x;
    py[j] = r.y;
    pz[j] = r.z;
    d[j] = __builtin_inff();
  }

  int last = 0;
  for (int it = 0; it < NPOINT; ++it) {
    // Selected point's coords: broadcast load from global (L2-hot).
    float4 sel = *reinterpret_cast<const float4*>(base + (size_t)last * CH);
    float sx = sel.x, sy = sel.y, sz = sel.z;
    if (tid == 0) {
      float* o = out + OFF_NEWXYZ + ((size_t)b * NPOINT + it) * 3;
      o[0] = sx;
      o[1] = sy;
      o[2] = sz;
    }
    float bestv = -1.0f;
    int besti = 0;
#pragma unroll
    for (int j = 0; j < PTS_PER_THREAD; ++j) {
      float dx = __fsub_rn(px[j], sx);
      float dy = __fsub_rn(py[j], sy);
      float dz = __fsub_rn(pz[j], sz);
      float nd = __fadd_rn(__fadd_rn(__fmul_rn(dx, dx), __fmul_rn(dy, dy)),
                           __fmul_rn(dz, dz));
      float dn = fminf(d[j], nd);
      d[j] = dn;
      if (dn > bestv) {  // strict: keeps lowest j (= lowest index) on ties
        bestv = dn;
        besti = tid + j * FPS_THREADS;
      }
    }
    // Wave butterfly argmax, tie -> lowest index.
#pragma unroll
    for (int off = 1; off < 64; off <<= 1) {
      float ov = __shfl_xor(bestv, off, 64);
      int oi = __shfl_xor(besti, off, 64);
      if (ov > bestv || (ov == bestv && oi < besti)) {
        bestv = ov;
        besti = oi;
      }
    }
    if (lane == 0) {
      redv[wv] = bestv;
      redi[wv] = besti;
    }
    __syncthreads();
    // Every thread redundantly reduces the 8 wave leaders (identical result,
    // avoids a broadcast round-trip).
    float gv = redv[0];
    int gi = redi[0];
#pragma unroll
    for (int w = 1; w < FPS_WAVES; ++w) {
      float v = redv[w];
      int i = redi[w];
      if (v > gv || (v == gv && i < gi)) {
        gv = v;
        gi = i;
      }
    }
    last = gi;
    __syncthreads();  // protect redv/redi before next iteration's overwrite
  }
}

// ---------------- Ball query + group: one wave per query -------------------
__device__ __forceinline__ void write_slot(float* __restrict__ out,
                                           const float* __restrict__ base,
                                           int b, int qi, int s, int p,
                                           float4 r0, float qx, float qy,
                                           float qz) {
  float dx = __fsub_rn(r0.x, qx);
  float dy = __fsub_rn(r0.y, qy);
  float dz = __fsub_rn(r0.z, qz);
  size_t qs = (size_t)b * NPOINT + qi;
  out[OFF_IDX + qs * NSAMPLE + s] = (float)p;  // idx stored as float32
  float* g = out + OFF_GXYZ + (qs * NSAMPLE + s) * 3;
  g[0] = dx;
  g[1] = dy;
  g[2] = dz;
  const float* row = base + (size_t)p * CH;
  float4 r1 = *reinterpret_cast<const float4*>(row + 4);
  float4 r2 = *reinterpret_cast<const float4*>(row + 8);
  float4 r3 = *reinterpret_cast<const float4*>(row + 12);
  float* np_ = out + OFF_NEWPTS + (qs * NSAMPLE + s) * CH;
  *reinterpret_cast<float4*>(np_ + 0) = make_float4(dx, dy, dz, r0.w);
  *reinterpret_cast<float4*>(np_ + 4) = r1;
  *reinterpret_cast<float4*>(np_ + 8) = r2;
  *reinterpret_cast<float4*>(np_ + 12) = r3;
}

__global__ __launch_bounds__(256) void ballq_kernel(
    const float* __restrict__ in, float* __restrict__ out) {
  const int lane = threadIdx.x & 63;
  const int qid = blockIdx.x * 4 + (threadIdx.x >> 6);
  const int b = qid >> 11;    // / NPOINT
  const int qi = qid & 2047;  // % NPOINT
  const float* base = in + (size_t)b * NPTS * CH;
  const float* q = out + OFF_NEWXYZ + ((size_t)b * NPOINT + qi) * 3;
  float qx = q[0], qy = q[1], qz = q[2];
  // Mirror reference: d2 = sum(q*q) + sum(p*p) - 2*(q . p)
  float qn = __fadd_rn(__fadd_rn(__fmul_rn(qx, qx), __fmul_rn(qy, qy)),
                       __fmul_rn(qz, qz));

  int cnt = 0;
  int first = 0;
  bool have_first = false;
  for (int chunk = 0; chunk < NPTS / 64 && cnt < NSAMPLE; ++chunk) {
    int p = chunk * 64 + lane;
    float4 r0 = *reinterpret_cast<const float4*>(base + (size_t)p * CH);
    float pn =
        __fadd_rn(__fadd_rn(__fmul_rn(r0.x, r0.x), __fmul_rn(r0.y, r0.y)),
                  __fmul_rn(r0.z, r0.z));
    float dot =
        __fadd_rn(__fadd_rn(__fmul_rn(qx, r0.x), __fmul_rn(qy, r0.y)),
                  __fmul_rn(qz, r0.z));
    float d2 = __fsub_rn(__fadd_rn(qn, pn), __fmul_rn(2.0f, dot));
    bool in_r = d2 < 1.0f;  // RADIUS^2
    unsigned long long mask = __ballot(in_r);
    if (!have_first && mask) {
      first = chunk * 64 + __builtin_ctzll(mask);
      have_first = true;
    }
    int pos = cnt + __popcll(mask & ((1ull << lane) - 1ull));
    if (in_r && pos < NSAMPLE) write_slot(out, base, b, qi, pos, p, r0, qx, qy, qz);
    cnt += __popcll(mask);
  }
  if (cnt < NSAMPLE) {
    // Pad remaining slots with the first in-radius index (reference fill rule).
    int s = cnt + lane;
    if (s < NSAMPLE) {
      float4 r0 = *reinterpret_cast<const float4*>(base + (size_t)first * CH);
      write_slot(out, base, b, qi, s, first, r0, qx, qy, qz);
    }
  }
}

extern "C" void kernel_launch(void* const* d_in, const int* in_sizes, int n_in,
                              void* d_out, int out_size, void* d_ws,
                              size_t ws_size, hipStream_t stream) {
  (void)in_sizes;
  (void)n_in;
  (void)out_size;
  (void)d_ws;
  (void)ws_size;
  const float* in = (const float*)d_in[0];
  float* out = (float*)d_out;
  fps_kernel<<<NB, FPS_THREADS, 0, stream>>>(in, out);
  ballq_kernel<<<(NB * NPOINT) / 4, 256, 0, stream>>>(in, out);
}